// Round 6
// baseline (242.605 us; speedup 1.0000x reference)
//
#include <hip/hip_runtime.h>
#include <math.h>

#define NB 8
#define NN 150
#define NE 299          // 2*N-1
#define NNODE (NB*NN)   // 1200

struct Quat { float w, x, y, z; };

__device__ inline Quat qmul(Quat a, Quat b) {
    Quat r;
    r.w = a.w*b.w - a.x*b.x - a.y*b.y - a.z*b.z;
    r.x = a.w*b.x + a.x*b.w + a.y*b.z - a.z*b.y;
    r.y = a.w*b.y - a.x*b.z + a.y*b.w + a.z*b.x;
    r.z = a.w*b.z + a.x*b.y - a.y*b.x + a.z*b.w;
    return r;
}
__device__ inline Quat qconj(Quat a) { return Quat{a.w, -a.x, -a.y, -a.z}; }

__device__ inline float3 qrot(Quat q, float3 v) {
    float tx = 2.f*(q.y*v.z - q.z*v.y);
    float ty = 2.f*(q.z*v.x - q.x*v.z);
    float tz = 2.f*(q.x*v.y - q.y*v.x);
    float cx = q.y*tz - q.z*ty;
    float cy = q.z*tx - q.x*tz;
    float cz = q.x*ty - q.y*tx;
    float3 r;
    r.x = v.x + q.w*tx + cx;
    r.y = v.y + q.w*ty + cy;
    r.z = v.z + q.w*tz + cz;
    return r;
}

// ---------------------------------------------------------------------------
// Pair kernel, one block per (b,i). 4 dispatches total (one per layer).
// FIRST: layer-1 node quantities (h_j, C_j, Cd_j, A_i, Ad_i) computed
// in-block; E-table terms computed inline (ed per thread, Gq/Etot on idle
// lanes) -> no init dispatch. Non-FIRST: identical to the proven round-4
// structure; tables for the NEXT layer are produced in the tail.
// ---------------------------------------------------------------------------
struct PairArgs {
    const float* qcur; const float* xcur;
    const float* feats; const int* tptr;               // FIRST only
    const float* hbuf; const float* Abuf;
    const float* Cin;  const float* Adin; const float* Cdin;
    const float* Ed;   const float* Gq;   const float* P;   // this-layer tables
    const float* wm;   const float* bmT;  const float* wqT; const float* bqT;
    const float* wf;   const float* bf;
    const float* wmN;  const float* bmN;  const float* wqN; const float* bqN;
    float* hout; float* Aout; float* Adout;
    float* Cout; float* Cdout;
    float* PN; float* EdN; float* GqN;                 // next-layer tables
    float* qout; float* xout; float* dout;
};

template<int HD, bool COMPUTE_O, bool WRITE_OUT, bool FIRST>
__global__ __launch_bounds__(192, 4) void pair_kernel(PairArgs a)
{
    constexpr int STR  = 196;                  // 192 cols + pad
    constexpr int NROW = COMPUTE_O ? 32 : 7;
    constexpr int NV   = COMPUTE_O ? 16 : 7;
    __shared__ __align__(16) float sMat[NROW*STR];
    __shared__ float sWmG[COMPUTE_O ? 288 : 4];
    __shared__ float sPr[192];
    __shared__ float sTot[16];
    __shared__ float sCs[32];
    __shared__ float sHi[64], sO[64], sMs[32];
    __shared__ float sGq[54], sAd[6];
    __shared__ float sA2[32], sC2[32];
    __shared__ float sWq[FIRST ? 192 : 1];
    __shared__ float sWmC[FIRST ? 960 : 1];
    __shared__ float sEtot[FIRST ? 32 : 1];

    const int tid   = threadIdx.x;
    const int nodeI = blockIdx.x;
    const int b     = nodeI / NN;
    const int i     = nodeI - b*NN;
    const int j     = tid;
    const float* Etab = a.wm + 2*HD*32;        // E rows of this layer's Wm

    // ---- staging ----
    if (COMPUTE_O) {
        for (int idx = tid; idx < 288; idx += 192) sWmG[idx] = a.wm[(2*HD+NE)*32 + idx];
        if (!FIRST)
            for (int idx = tid; idx < HD; idx += 192) sHi[idx] = a.hbuf[nodeI*64 + idx];
    }
    if (FIRST) {
        sWq[tid] = a.wqT[tid];
        for (int idx = tid; idx < 960; idx += 192) sWmC[idx] = a.wm[HD*32 + idx];
        if (tid < 30) {
            float v;
            if      (tid < 4)  v = a.qcur[nodeI*4 + tid];
            else if (tid < 7)  v = a.xcur[nodeI*3 + (tid-4)];
            else if (tid < 29) v = a.feats[nodeI*22 + (tid-7)];
            else               v = (float)a.tptr[0] * (1.0f/1000.0f);
            sHi[tid] = v;
        }
    } else {
        if (tid < 54) sGq[tid] = a.Gq[tid];
        if (tid < 6)  sAd[tid] = a.Adin[nodeI*8 + tid];
    }
    __syncthreads();   // B0

    const float4 qi4 = ((const float4*)a.qcur)[nodeI];
    const Quat  qi = {qi4.x, qi4.y, qi4.z, qi4.w};
    const float3 xi = {a.xcur[nodeI*3+0], a.xcur[nodeI*3+1], a.xcur[nodeI*3+2]};

    const bool act = (j < NN);
    const int nodeJ = b*NN + j;
    const float mm = (j == i) ? 0.f : 1.f;

    Quat qj = {1.f,0.f,0.f,0.f};
    float3 xj = {0.f,0.f,0.f};
    float cj[FIRST ? 32 : 1];
    float cdj6[FIRST ? 6 : 1];

    if (FIRST) {
        // per-j layer-1 node work, fully local
        if (act) {
            float hj[30];
            const float4 q4 = ((const float4*)a.qcur)[nodeJ];
            hj[0]=q4.x; hj[1]=q4.y; hj[2]=q4.z; hj[3]=q4.w;
            hj[4]=a.xcur[nodeJ*3+0]; hj[5]=a.xcur[nodeJ*3+1]; hj[6]=a.xcur[nodeJ*3+2];
#pragma unroll
            for (int d2 = 0; d2 < 22; ++d2) hj[7+d2] = a.feats[nodeJ*22 + d2];
            hj[29] = (float)a.tptr[0] * (1.0f/1000.0f);
            qj = Quat{hj[0],hj[1],hj[2],hj[3]};
            xj = float3{hj[4],hj[5],hj[6]};
#pragma unroll
            for (int k = 0; k < 32; ++k) cj[k] = 0.f;
#pragma unroll
            for (int d2 = 0; d2 < 30; ++d2) {
                const float hv = hj[d2];
#pragma unroll
                for (int k = 0; k < 32; ++k) cj[k] = fmaf(hv, sWmC[d2*32+k], cj[k]);
            }
#pragma unroll
            for (int d2 = 0; d2 < 6; ++d2) {
                float acc = 0.f;
#pragma unroll
                for (int k = 0; k < 32; ++k) acc = fmaf(cj[k], sWq[k*6+d2], acc);
                cdj6[d2] = acc;
            }
        }
        if (tid < 32) {          // A_i
            float acc = a.bmT[tid];
#pragma unroll
            for (int d2 = 0; d2 < 30; ++d2) acc = fmaf(sHi[d2], a.wm[d2*32+tid], acc);
            sA2[tid] = acc;
        }
        if (tid >= 150) {        // idle lanes: Gq
            for (int tt = tid-150; tt < 54; tt += 42) {
                const int tr = tt/6, dd = tt - tr*6;
                float acc = 0.f;
#pragma unroll
                for (int k = 0; k < 32; ++k) acc = fmaf(Etab[(NE+tr)*32+k], sWq[k*6+dd], acc);
                sGq[tt] = acc;
            }
        }
        if (tid >= 160) {        // idle lanes: Etot = sum_{j!=i} E_row(149+i-j)
            const int k = tid-160;
            float acc = -Etab[(NN-1)*32 + k];
            for (int r = i; r < i+NN; ++r) acc += Etab[r*32 + k];
            sEtot[k] = acc;
        }
        __syncthreads();         // B1: sA2, sGq ready
        if (tid < 6) {           // Ad_i
            float acc = a.bqT[tid];
#pragma unroll
            for (int k = 0; k < 32; ++k) acc = fmaf(sA2[k], sWq[k*6+tid], acc);
            sAd[tid] = acc;
        }
        __syncthreads();         // B2: sAd ready
    } else {
        if (act) {
            const float4 q4 = ((const float4*)a.qcur)[nodeJ];
            qj = Quat{q4.x, q4.y, q4.z, q4.w};
            xj = float3{a.xcur[nodeJ*3+0], a.xcur[nodeJ*3+1], a.xcur[nodeJ*3+2]};
        }
    }

    // ---- geometry + factored delta ----
    float vals[NV];
#pragma unroll
    for (int v = 0; v < NV; ++v) vals[v] = 0.f;

    if (act) {
        float3 diff = {xi.x - xj.x, xi.y - xj.y, xi.z - xj.z};
        Quat qjc = qconj(qj);
        float3 lx = qrot(qjc, diff);
        Quat lq = qmul(qmul(qjc, qi), qj);
        const float d2v = diff.x*diff.x + diff.y*diff.y + diff.z*diff.z;
        const float dt = fabsf(qi.w*qj.w + qi.x*qj.x + qi.y*qj.y + qi.z*qj.z);
        const float g[9] = {lx.x, lx.y, lx.z, lq.w, lq.x, lq.y, lq.z, d2v, dt};

        float delta[6];
        if (FIRST) {
#pragma unroll
            for (int d2 = 0; d2 < 6; ++d2) delta[d2] = sAd[d2] + cdj6[d2];
            const float* Er = Etab + (NN-1 + i - j)*32;   // ed inline
#pragma unroll
            for (int k = 0; k < 32; ++k) {
                const float ev = Er[k];
#pragma unroll
                for (int d2 = 0; d2 < 6; ++d2)
                    delta[d2] = fmaf(ev, sWq[k*6+d2], delta[d2]);
            }
        } else {
            const float4* cd4 = (const float4*)(a.Cdin + nodeJ*8);
            const float4* ed4 = (const float4*)(a.Ed + (NN-1 + i - j)*8);
            const float4 c0 = cd4[0], c1 = cd4[1];
            const float4 e0 = ed4[0], e1 = ed4[1];
            delta[0] = sAd[0] + c0.x + e0.x;
            delta[1] = sAd[1] + c0.y + e0.y;
            delta[2] = sAd[2] + c0.z + e0.z;
            delta[3] = sAd[3] + c0.w + e0.w;
            delta[4] = sAd[4] + c1.x + e1.x;
            delta[5] = sAd[5] + c1.y + e1.y;
        }
#pragma unroll
        for (int t = 0; t < 9; ++t) {
            const float gv = g[t];
#pragma unroll
            for (int d2 = 0; d2 < 6; ++d2)
                delta[d2] = fmaf(gv, sGq[t*6 + d2], delta[d2]);
        }
#pragma unroll
        for (int d2 = 0; d2 < 6; ++d2) delta[d2] *= mm;

        constexpr int vo = COMPUTE_O ? 9 : 0;
        if (COMPUTE_O) {
#pragma unroll
            for (int t = 0; t < 9; ++t) vals[t] = g[t]*mm;
        }
        float3 dv = {delta[3], delta[4], delta[5]};
        float3 rd = qrot(qj, dv);
        vals[vo+0] = rd.x; vals[vo+1] = rd.y; vals[vo+2] = rd.z;
        Quat vq = {0.f, delta[0], delta[1], delta[2]};
        Quat sp = qmul(lq, vq);
        vals[vo+3] = lq.w + sp.w;
        vals[vo+4] = lq.x + sp.x;
        vals[vo+5] = lq.y + sp.y;
        vals[vo+6] = lq.z + sp.z;
    }

    // ---- pass A: vals rows 0..NV-1 + C[0:16] rows 16..31 ----
#pragma unroll
    for (int v = 0; v < NV; ++v) sMat[v*STR + tid] = vals[v];
    if (COMPUTE_O) {
        if (FIRST) {
            if (act) {
#pragma unroll
                for (int r = 0; r < 16; ++r) sMat[(16+r)*STR + tid] = cj[r]*mm;
            } else {
#pragma unroll
                for (int r = 16; r < 32; ++r) sMat[r*STR + tid] = 0.f;
            }
        } else {
            if (act) {
                const float4* c4p = (const float4*)(a.Cin + nodeJ*32);
#pragma unroll
                for (int q = 0; q < 4; ++q) {
                    const float4 c = c4p[q];
                    sMat[(16+4*q+0)*STR + tid] = c.x*mm;
                    sMat[(16+4*q+1)*STR + tid] = c.y*mm;
                    sMat[(16+4*q+2)*STR + tid] = c.z*mm;
                    sMat[(16+4*q+3)*STR + tid] = c.w*mm;
                }
            } else {
#pragma unroll
                for (int r = 16; r < 32; ++r) sMat[r*STR + tid] = 0.f;
            }
        }
    }
    __syncthreads();
    if (tid < 4*NROW) {
        const int ch = tid >> 2, q4 = tid & 3;
        const float4* row = (const float4*)(sMat + ch*STR + q4*48);
        float s0 = 0.f, s1 = 0.f, s2 = 0.f, s3 = 0.f;
#pragma unroll
        for (int it = 0; it < 12; ++it) {
            const float4 r = row[it];
            s0 += r.x; s1 += r.y; s2 += r.z; s3 += r.w;
        }
        sPr[tid] = (s0+s1) + (s2+s3);
    }
    __syncthreads();

    // ---- pass B: C[16:32] on rows 0..15 ----
    if (COMPUTE_O) {
        if (FIRST) {
            if (act) {
#pragma unroll
                for (int r = 0; r < 16; ++r) sMat[r*STR + tid] = cj[16+r]*mm;
            } else {
#pragma unroll
                for (int r = 0; r < 16; ++r) sMat[r*STR + tid] = 0.f;
            }
        } else {
            if (act) {
                const float4* c4p = (const float4*)(a.Cin + nodeJ*32);
#pragma unroll
                for (int q = 0; q < 4; ++q) {
                    const float4 c = c4p[4+q];
                    sMat[(4*q+0)*STR + tid] = c.x*mm;
                    sMat[(4*q+1)*STR + tid] = c.y*mm;
                    sMat[(4*q+2)*STR + tid] = c.z*mm;
                    sMat[(4*q+3)*STR + tid] = c.w*mm;
                }
            } else {
#pragma unroll
                for (int r = 0; r < 16; ++r) sMat[r*STR + tid] = 0.f;
            }
        }
        __syncthreads();
        if (tid < 64) {
            const int ch = tid >> 2, q4 = tid & 3;
            const float4* row = (const float4*)(sMat + ch*STR + q4*48);
            float s0 = 0.f, s1 = 0.f, s2 = 0.f, s3 = 0.f;
#pragma unroll
            for (int it = 0; it < 12; ++it) {
                const float4 r = row[it];
                s0 += r.x; s1 += r.y; s2 += r.z; s3 += r.w;
            }
            sPr[128 + tid] = (s0+s1) + (s2+s3);
        }
        __syncthreads();
    }

    // ---- totals ----
    if (COMPUTE_O) {
        if (tid < 16)
            sTot[tid] = (sPr[4*tid] + sPr[4*tid+1]) + (sPr[4*tid+2] + sPr[4*tid+3]);
        else if (tid < 32) {
            const int c = tid - 16, o4 = 64 + 4*c;
            sCs[c] = (sPr[o4] + sPr[o4+1]) + (sPr[o4+2] + sPr[o4+3]);
        } else if (tid < 48) {
            const int c = tid - 16, o4 = 128 + 4*(tid-32);
            sCs[c] = (sPr[o4] + sPr[o4+1]) + (sPr[o4+2] + sPr[o4+3]);
        }
    } else {
        if (tid < 7)
            sTot[tid] = (sPr[4*tid] + sPr[4*tid+1]) + (sPr[4*tid+2] + sPr[4*tid+3]);
    }
    __syncthreads();

    if (COMPUTE_O) {
        if (tid < 32) {
            const int k = tid;
            float ms;
            if (FIRST)
                ms = 149.f*sA2[k] + sCs[k] + sEtot[k];
            else
                ms = 149.f*a.Abuf[nodeI*32 + k] + sCs[k]
                   + a.P[(i+NN)*32 + k] - a.P[i*32 + k]
                   - a.wm[(2*HD + (NN-1))*32 + k];
#pragma unroll
            for (int t = 0; t < 9; ++t) ms = fmaf(sTot[t], sWmG[t*32 + k], ms);
            sMs[k] = ms;
        }
        __syncthreads();
        if (tid < 64) {
            float acc0 = a.bf[tid], acc1 = 0.f;
#pragma unroll 8
            for (int d2 = 0; d2 < HD; d2 += 2) {
                acc0 = fmaf(sHi[d2],   a.wf[d2*64 + tid],     acc0);
                acc1 = fmaf(sHi[d2+1], a.wf[(d2+1)*64 + tid], acc1);
            }
#pragma unroll 8
            for (int k = 0; k < 32; k += 2) {
                acc0 = fmaf(sMs[k],   a.wf[(HD+k)*64 + tid],   acc0);
                acc1 = fmaf(sMs[k+1], a.wf[(HD+k+1)*64 + tid], acc1);
            }
            sO[tid] = acc0 + acc1;
        }
    }

    // ---- q/x epilogue ----
    if (tid == 0) {
        constexpr int XO = COMPUTE_O ? 9 : 0;
        const float inv = 1.0f / (float)(NN - 1);
        const float ux0 = ((float)NN * xi.x + sTot[XO+0]) * inv;
        const float ux1 = ((float)NN * xi.y + sTot[XO+1]) * inv;
        const float ux2 = ((float)NN * xi.z + sTot[XO+2]) * inv;
        Quat s = {sTot[XO+3], sTot[XO+4], sTot[XO+5], sTot[XO+6]};
        const float nrm = sqrtf(s.w*s.w + s.x*s.x + s.y*s.y + s.z*s.z);
        const float invn = 1.0f / fmaxf(nrm, 1e-12f);
        Quat u = {s.w*invn, s.x*invn, s.y*invn, s.z*invn};
        Quat uq = qmul(qmul(qi, u), qconj(qi));
        if (WRITE_OUT) {
            float* op = a.dout + nodeI*7;
            op[0] = uq.w; op[1] = uq.x; op[2] = uq.y; op[3] = uq.z;
            op[4] = ux0;  op[5] = ux1;  op[6] = ux2;
        } else {
            a.qout[nodeI*4+0] = uq.w; a.qout[nodeI*4+1] = uq.x;
            a.qout[nodeI*4+2] = uq.y; a.qout[nodeI*4+3] = uq.z;
            a.xout[nodeI*3+0] = ux0;  a.xout[nodeI*3+1] = ux1;
            a.xout[nodeI*3+2] = ux2;
        }
    }

    // ---- tail: next layer's node work + next-layer tables ----
    if (COMPUTE_O) {
        __syncthreads();            // sO ready
        if (tid < 64) {
            const float hn = fmaxf(sO[tid], 0.f);   // relu
            sHi[tid] = hn;
            a.hout[nodeI*64 + tid] = hn;
        }
        __syncthreads();
        if (tid < 64) {
            const int k   = tid & 31;
            const int off = (tid >= 32) ? 64 : 0;
            float acc = (tid < 32) ? a.bmN[k] : 0.f;
#pragma unroll
            for (int d2 = 0; d2 < 64; ++d2) acc = fmaf(sHi[d2], a.wmN[(off+d2)*32 + k], acc);
            if (tid < 32) { a.Aout[nodeI*32 + k] = acc; sA2[k] = acc; }
            else          { a.Cout[nodeI*32 + k] = acc; sC2[k] = acc; }
        }
        __syncthreads();
        if (tid < 12) {
            const int half = (tid >= 6) ? 1 : 0;
            const int d2 = tid - half*6;
            const float* src = half ? sC2 : sA2;
            float acc = half ? 0.f : a.bqN[d2];
#pragma unroll
            for (int k = 0; k < 32; ++k) acc = fmaf(src[k], a.wqN[k*6 + d2], acc);
            (half ? a.Cdout : a.Adout)[nodeI*8 + d2] = acc;
        }

        // next-layer weight tables (consumed by the following dispatch)
        const float* EN = a.wmN + 2*64*32;
        if (nodeI < NE && tid >= 64 && tid < 70) {
            const int dd = tid - 64;
            float acc = 0.f;
#pragma unroll
            for (int k = 0; k < 32; ++k) acc = fmaf(EN[nodeI*32+k], a.wqN[k*6+dd], acc);
            a.EdN[nodeI*8+dd] = acc;
        }
        if (nodeI == 1100 && tid >= 64 && tid < 118) {
            const int tt = tid-64; const int tr = tt/6, dd = tt - tr*6;
            float acc = 0.f;
#pragma unroll
            for (int k = 0; k < 32; ++k) acc = fmaf(EN[(NE+tr)*32+k], a.wqN[k*6+dd], acc);
            a.GqN[tr*6+dd] = acc;
        }
        if (nodeI == 1101) {        // P prefix scan for next layer
            __syncthreads();
            const int gp = tid >> 5, k = tid & 31;   // 6 groups x 32 channels
            const int r0 = gp*50;
            float part = 0.f;
            for (int r = r0; r < r0+50 && r < NE; ++r) part += EN[r*32 + k];
            sPr[gp*32 + k] = part;
            __syncthreads();
            float run = 0.f;
            for (int gg = 0; gg < gp; ++gg) run += sPr[gg*32 + k];
            for (int r = r0; r < r0+50; ++r) {
                a.PN[r*32 + k] = run;
                if (r < NE) run += EN[r*32 + k];
            }
        }
    }
}

// ---------------------------------------------------------------------------

extern "C" void kernel_launch(void* const* d_in, const int* in_sizes, int n_in,
                              void* d_out, int out_size, void* d_ws, size_t ws_size,
                              hipStream_t stream) {
    const float* quats = (const float*)d_in[0];
    const float* trans = (const float*)d_in[1];
    const float* wm[4] = {(const float*)d_in[5],  (const float*)d_in[11],
                          (const float*)d_in[17], (const float*)d_in[23]};
    const float* bm[4] = {(const float*)d_in[6],  (const float*)d_in[12],
                          (const float*)d_in[18], (const float*)d_in[24]};
    const float* wf[4] = {(const float*)d_in[7],  (const float*)d_in[13],
                          (const float*)d_in[19], (const float*)d_in[25]};
    const float* bf[4] = {(const float*)d_in[8],  (const float*)d_in[14],
                          (const float*)d_in[20], (const float*)d_in[26]};
    const float* wq[4] = {(const float*)d_in[9],  (const float*)d_in[15],
                          (const float*)d_in[21], (const float*)d_in[27]};
    const float* bq[4] = {(const float*)d_in[10], (const float*)d_in[16],
                          (const float*)d_in[22], (const float*)d_in[28]};

    float* ws = (float*)d_ws;
    float* h   = ws;               // 1200*64
    float* A   = h   + NNODE*64;   // 1200*32
    float* CA  = A   + NNODE*32;   // 1200*32
    float* CB  = CA  + NNODE*32;   // 1200*32
    float* Ad  = CB  + NNODE*32;   // 1200*8
    float* CdA = Ad  + NNODE*8;    // 1200*8
    float* CdB = CdA + NNODE*8;    // 1200*8
    float* qA  = CdB + NNODE*8;    // 1200*4
    float* xA  = qA  + NNODE*4;    // 1200*3
    float* qB  = xA  + NNODE*3;    // 1200*4
    float* xB  = qB  + NNODE*4;    // 1200*3
    float* Pp  = xB  + NNODE*3;    // 4*300*32 (regions 1..3 used)
    float* Edp = Pp  + 4*9600;     // 4*300*8
    float* Gqp = Edp + 4*2400;     // 4*64

    PairArgs p;
    p.feats = (const float*)d_in[2];
    p.tptr  = (const int*)d_in[4];
    p.dout  = (float*)d_out;

    // ---- P1: layer 1 (FIRST) + node L2 tail + L2 tables ----
    p.qcur = quats; p.xcur = trans;
    p.hbuf = nullptr; p.Abuf = nullptr; p.Cin = nullptr;
    p.Adin = nullptr; p.Cdin = nullptr;
    p.Ed = nullptr; p.Gq = nullptr; p.P = nullptr;
    p.wm = wm[0]; p.bmT = bm[0]; p.wqT = wq[0]; p.bqT = bq[0];
    p.wf = wf[0]; p.bf = bf[0];
    p.wmN = wm[1]; p.bmN = bm[1]; p.wqN = wq[1]; p.bqN = bq[1];
    p.hout = h; p.Aout = A; p.Adout = Ad; p.Cout = CA; p.Cdout = CdA;
    p.PN = Pp + 1*9600; p.EdN = Edp + 1*2400; p.GqN = Gqp + 1*64;
    p.qout = qA; p.xout = xA;
    pair_kernel<30, true, false, true><<<dim3(NNODE), dim3(192), 0, stream>>>(p);

    // ---- P2: layer 2 + node L3 tail + L3 tables ----
    p.qcur = qA; p.xcur = xA;
    p.hbuf = h; p.Abuf = A; p.Cin = CA; p.Adin = Ad; p.Cdin = CdA;
    p.Ed = Edp + 1*2400; p.Gq = Gqp + 1*64; p.P = Pp + 1*9600;
    p.wm = wm[1]; p.bmT = bm[1]; p.wqT = wq[1]; p.bqT = bq[1];
    p.wf = wf[1]; p.bf = bf[1];
    p.wmN = wm[2]; p.bmN = bm[2]; p.wqN = wq[2]; p.bqN = bq[2];
    p.Cout = CB; p.Cdout = CdB;
    p.PN = Pp + 2*9600; p.EdN = Edp + 2*2400; p.GqN = Gqp + 2*64;
    p.qout = qB; p.xout = xB;
    pair_kernel<64, true, false, false><<<dim3(NNODE), dim3(192), 0, stream>>>(p);

    // ---- P3: layer 3 + node L4 tail + L4 tables ----
    p.qcur = qB; p.xcur = xB;
    p.Cin = CB; p.Cdin = CdB;
    p.Ed = Edp + 2*2400; p.Gq = Gqp + 2*64; p.P = Pp + 2*9600;
    p.wm = wm[2]; p.bmT = bm[2]; p.wqT = wq[2]; p.bqT = bq[2];
    p.wf = wf[2]; p.bf = bf[2];
    p.wmN = wm[3]; p.bmN = bm[3]; p.wqN = wq[3]; p.bqN = bq[3];
    p.Cout = CA; p.Cdout = CdA;
    p.PN = Pp + 3*9600; p.EdN = Edp + 3*2400; p.GqN = Gqp + 3*64;
    p.qout = qA; p.xout = xA;
    pair_kernel<64, true, false, false><<<dim3(NNODE), dim3(192), 0, stream>>>(p);

    // ---- P4: layer 4 -> d_out ----
    p.qcur = qA; p.xcur = xA;
    p.Cin = CA; p.Cdin = CdA; p.Adin = Ad;
    p.Ed = Edp + 3*2400; p.Gq = Gqp + 3*64; p.P = Pp + 3*9600;
    p.wm = wm[3]; p.bmT = bm[3]; p.wqT = wq[3]; p.bqT = bq[3];
    p.wf = wf[3]; p.bf = bf[3];
    p.wmN = wm[3]; p.bmN = bm[3]; p.wqN = wq[3]; p.bqN = bq[3];  // unused
    p.qout = nullptr; p.xout = nullptr;
    pair_kernel<64, false, true, false><<<dim3(NNODE), dim3(192), 0, stream>>>(p);
}

// Round 7
// 165.387 us; speedup vs baseline: 1.4669x; 1.4669x over previous
//
#include <hip/hip_runtime.h>
#include <math.h>

#define NB 8
#define NN 150
#define NE 299          // 2*N-1
#define NNODE (NB*NN)   // 1200

struct Quat { float w, x, y, z; };

__device__ inline Quat qmul(Quat a, Quat b) {
    Quat r;
    r.w = a.w*b.w - a.x*b.x - a.y*b.y - a.z*b.z;
    r.x = a.w*b.x + a.x*b.w + a.y*b.z - a.z*b.y;
    r.y = a.w*b.y - a.x*b.z + a.y*b.w + a.z*b.x;
    r.z = a.w*b.z + a.x*b.y - a.y*b.x + a.z*b.w;
    return r;
}
__device__ inline Quat qconj(Quat a) { return Quat{a.w, -a.x, -a.y, -a.z}; }

__device__ inline float3 qrot(Quat q, float3 v) {
    float tx = 2.f*(q.y*v.z - q.z*v.y);
    float ty = 2.f*(q.z*v.x - q.x*v.z);
    float tz = 2.f*(q.x*v.y - q.y*v.x);
    float cx = q.y*tz - q.z*ty;
    float cy = q.z*tx - q.x*tz;
    float cz = q.x*ty - q.y*tx;
    float3 r;
    r.x = v.x + q.w*tx + cx;
    r.y = v.y + q.w*ty + cy;
    r.z = v.z + q.w*tz + cz;
    return r;
}

// ---------------------------------------------------------------------------
// D1: layer-1 node work (blocks 0..149, 8 nodes each) + per-layer tables:
//   150..153 : P[l][300][32] prefix sums of E rows of Wm
//   154..157 : Gq[l][9][6] = geom rows @ Wq
//   158..257 : Ed[l][299][8] = E rows @ Wq
//   258      : Csum1 = (sum_j h_j) @ WmC (factored), zero Csum2..4
// ---------------------------------------------------------------------------
struct InitArgs {
    const float* quats; const float* trans; const float* feats; const int* tptr;
    const float* wm[4]; const float* wq[4];
    const float* bm1; const float* bq1;
    float* h; float* A; float* C0; float* Ad; float* Cd0;
    float* P; float* Ed; float* Gq; float* Csum;
};

__global__ __launch_bounds__(256) void init_kernel(InitArgs a)
{
    __shared__ float sh[8][30];
    __shared__ float sA[8][32];
    __shared__ float sC[8][32];
    __shared__ float sPS[256];
    const int tid = threadIdx.x;
    const int blk = blockIdx.x;

    if (blk < 150) {
        const int nodeBase = blk*8;
        for (int idx = tid; idx < 8*30; idx += 256) {
            const int nl = idx / 30;
            const int d  = idx - nl*30;
            const int n  = nodeBase + nl;
            float v;
            if      (d < 4)  v = a.quats[n*4 + d];
            else if (d < 7)  v = a.trans[n*3 + (d-4)];
            else if (d < 29) v = a.feats[n*22 + (d-7)];
            else             v = (float)a.tptr[0] * (1.0f/1000.0f);
            sh[nl][d] = v;
            a.h[n*64 + d] = v;
        }
        __syncthreads();
        {
            const int nl = tid >> 5;
            const int k  = tid & 31;
            const int n  = nodeBase + nl;
            float av = a.bm1[k], cv = 0.f;
#pragma unroll
            for (int d = 0; d < 30; ++d) {
                const float hv = sh[nl][d];
                av = fmaf(hv, a.wm[0][d*32 + k], av);
                cv = fmaf(hv, a.wm[0][(30+d)*32 + k], cv);
            }
            a.A[n*32 + k]  = av;
            a.C0[n*32 + k] = cv;
            sA[nl][k] = av;
            sC[nl][k] = cv;
        }
        __syncthreads();
        if (tid < 96) {
            const int half = (tid >= 48) ? 1 : 0;
            const int idx  = tid - half*48;
            const int nl = idx / 6;
            const int d  = idx - nl*6;
            const float* src = half ? sC[nl] : sA[nl];
            float acc = half ? 0.f : a.bq1[d];
#pragma unroll
            for (int k = 0; k < 32; ++k) acc = fmaf(src[k], a.wq[0][k*6 + d], acc);
            (half ? a.Cd0 : a.Ad)[(nodeBase+nl)*8 + d] = acc;
        }
    } else if (blk < 154) {
        const int l = blk - 150;
        const int HDl = (l == 0) ? 30 : 64;
        const float* E = a.wm[l] + 2*HDl*32;
        float* Pl = a.P + l*9600;
        const int g = tid >> 5, k = tid & 31;    // 8 groups x 32 channels
        const int r0 = g*38;
        float part = 0.f;
        for (int r = r0; r < r0+38 && r < NE; ++r) part += E[r*32 + k];
        sPS[g*32 + k] = part;
        __syncthreads();
        float run = 0.f;
        for (int gg = 0; gg < g; ++gg) run += sPS[gg*32 + k];
        const int rw = (r0+38 < 300) ? r0+38 : 300;
        for (int r = r0; r < rw; ++r) {
            Pl[r*32 + k] = run;
            if (r < NE) run += E[r*32 + k];
        }
    } else if (blk < 158) {
        const int l = blk - 154;
        const int HDl = (l == 0) ? 30 : 64;
        const float* E  = a.wm[l] + 2*HDl*32;
        const float* Wq = a.wq[l];
        if (tid < 54) {
            const int t = tid/6, d = tid - t*6;
            float acc = 0.f;
#pragma unroll
            for (int k = 0; k < 32; ++k) acc = fmaf(E[(NE+t)*32 + k], Wq[k*6 + d], acc);
            a.Gq[l*64 + t*6 + d] = acc;
        }
    } else if (blk < 258) {
        const int bb = blk - 158;              // 0..99
        const int l = bb / 25;
        const int rbase = (bb % 25) * 12;
        const int HDl = (l == 0) ? 30 : 64;
        const float* E  = a.wm[l] + 2*HDl*32;
        const float* Wq = a.wq[l];
        if (tid < 72) {
            const int rr = tid/6, d = tid - rr*6;
            const int r = rbase + rr;
            if (r < NE) {
                float acc = 0.f;
#pragma unroll
                for (int k = 0; k < 32; ++k) acc = fmaf(E[r*32 + k], Wq[k*6 + d], acc);
                a.Ed[l*2400 + r*8 + d] = acc;
            }
        }
    } else {
        // Csum1 via factorization: Csum1[b][k] = sum_d Hsum[b][d]*WmC[d][k]
        if (tid < 240) {
            const int bb = tid/30, d = tid - bb*30;
            float acc = 0.f;
            if (d < 4)       { for (int jj=0;jj<NN;++jj) acc += a.quats[(bb*NN+jj)*4 + d]; }
            else if (d < 7)  { for (int jj=0;jj<NN;++jj) acc += a.trans[(bb*NN+jj)*3 + (d-4)]; }
            else if (d < 29) { for (int jj=0;jj<NN;++jj) acc += a.feats[(bb*NN+jj)*22 + (d-7)]; }
            else             { acc = (float)NN * ((float)a.tptr[0] * (1.0f/1000.0f)); }
            sh[bb][d] = acc;
        }
        a.Csum[256 + tid] = 0.f;     // zero layers 2..4
        a.Csum[512 + tid] = 0.f;
        a.Csum[768 + tid] = 0.f;
        __syncthreads();
        const int bb = tid >> 5, k = tid & 31;
        float acc = 0.f;
#pragma unroll
        for (int d = 0; d < 30; ++d) acc = fmaf(sh[bb][d], a.wm[0][(30+d)*32 + k], acc);
        a.Csum[bb*32 + k] = acc;
    }
}

// ---------------------------------------------------------------------------
// Thin pair kernel: one block per (b,i). Geometry + factored 6-channel delta;
// single-pass 16-row LDS-transpose reduce (no C channels -> Csum algebra);
// msum reconstructed; o; next-layer node tail (+ Csum atomicAdd).
// ---------------------------------------------------------------------------
struct PairArgs {
    const float* qcur; const float* xcur;
    const float* hbuf; const float* Abuf; const float* Cin;
    const float* Adin; const float* Cdin;
    const float* Ed; const float* Gq; const float* P; const float* Csum;
    const float* wm; const float* wf; const float* bf;
    const float* wmN; const float* bmN; const float* wqN; const float* bqN;
    float* hout; float* Aout; float* Adout; float* Cout; float* Cdout;
    float* CsumN;
    float* qout; float* xout; float* dout;
};

template<int HD, bool COMPUTE_O, bool WRITE_OUT, bool TAIL_FULL>
__global__ __launch_bounds__(192, 5) void pair_kernel(PairArgs a)
{
    constexpr int STR = 196;                  // 192 cols + pad
    constexpr int NV  = COMPUTE_O ? 16 : 7;
    __shared__ __align__(16) float sMat[NV*STR];
    __shared__ float sPr[64];
    __shared__ float sTot[16];
    __shared__ float sHi[64], sO[64], sMs[32];
    __shared__ float sGq[54], sAd[6];
    __shared__ float sA2[32], sC2[32];

    const int tid   = threadIdx.x;
    const int nodeI = blockIdx.x;
    const int b     = nodeI / NN;
    const int i     = nodeI - b*NN;
    const int j     = tid;

    // ---- staging ----
    if (COMPUTE_O) { if (tid < HD) sHi[tid] = a.hbuf[nodeI*64 + tid]; }
    if (tid < 54) sGq[tid] = a.Gq[tid];
    if (tid >= 64 && tid < 70) sAd[tid-64] = a.Adin[nodeI*8 + (tid-64)];
    __syncthreads();   // B0

    const float4 qi4 = ((const float4*)a.qcur)[nodeI];
    const Quat  qi = {qi4.x, qi4.y, qi4.z, qi4.w};
    const float3 xi = {a.xcur[nodeI*3+0], a.xcur[nodeI*3+1], a.xcur[nodeI*3+2]};

    float vals[NV];
#pragma unroll
    for (int v = 0; v < NV; ++v) vals[v] = 0.f;

    if (j < NN) {
        const int nodeJ = b*NN + j;
        const float4 q4 = ((const float4*)a.qcur)[nodeJ];
        Quat qj = {q4.x, q4.y, q4.z, q4.w};
        float3 xj = {a.xcur[nodeJ*3+0], a.xcur[nodeJ*3+1], a.xcur[nodeJ*3+2]};
        const float mm = (j == i) ? 0.f : 1.f;

        float3 diff = {xi.x - xj.x, xi.y - xj.y, xi.z - xj.z};
        Quat qjc = qconj(qj);
        float3 lx = qrot(qjc, diff);
        Quat lq = qmul(qmul(qjc, qi), qj);
        const float d2v = diff.x*diff.x + diff.y*diff.y + diff.z*diff.z;
        const float dt = fabsf(qi.w*qj.w + qi.x*qj.x + qi.y*qj.y + qi.z*qj.z);
        const float g[9] = {lx.x, lx.y, lx.z, lq.w, lq.x, lq.y, lq.z, d2v, dt};

        // delta = Ad_i + Cd_j + Ed_{i-j} + sum_t g[t]*Gq[t]   (then *mm)
        const float4* cd4 = (const float4*)(a.Cdin + nodeJ*8);
        const float4* ed4 = (const float4*)(a.Ed + (NN-1 + i - j)*8);
        const float4 c0 = cd4[0], c1 = cd4[1];
        const float4 e0 = ed4[0], e1 = ed4[1];
        float delta[6];
        delta[0] = sAd[0] + c0.x + e0.x;
        delta[1] = sAd[1] + c0.y + e0.y;
        delta[2] = sAd[2] + c0.z + e0.z;
        delta[3] = sAd[3] + c0.w + e0.w;
        delta[4] = sAd[4] + c1.x + e1.x;
        delta[5] = sAd[5] + c1.y + e1.y;
#pragma unroll
        for (int t = 0; t < 9; ++t) {
            const float gv = g[t];
#pragma unroll
            for (int d2 = 0; d2 < 6; ++d2)
                delta[d2] = fmaf(gv, sGq[t*6 + d2], delta[d2]);
        }
#pragma unroll
        for (int d2 = 0; d2 < 6; ++d2) delta[d2] *= mm;

        constexpr int vo = COMPUTE_O ? 9 : 0;
        if (COMPUTE_O) {
#pragma unroll
            for (int t = 0; t < 9; ++t) vals[t] = g[t]*mm;   // Gsum excl j==i
        }
        float3 dv = {delta[3], delta[4], delta[5]};
        float3 rd = qrot(qj, dv);
        vals[vo+0] = rd.x; vals[vo+1] = rd.y; vals[vo+2] = rd.z;
        Quat vq = {0.f, delta[0], delta[1], delta[2]};
        Quat sp = qmul(lq, vq);
        vals[vo+3] = lq.w + sp.w;
        vals[vo+4] = lq.x + sp.x;
        vals[vo+5] = lq.y + sp.y;
        vals[vo+6] = lq.z + sp.z;
    }

    // ---- single-pass LDS-transpose reduce ----
#pragma unroll
    for (int v = 0; v < NV; ++v) sMat[v*STR + tid] = vals[v];
    __syncthreads();   // B1
    if (tid < 4*NV) {
        const int ch = tid >> 2, q4i = tid & 3;
        const float4* row = (const float4*)(sMat + ch*STR + q4i*48);
        float s0 = 0.f, s1 = 0.f, s2 = 0.f, s3 = 0.f;
#pragma unroll
        for (int it = 0; it < 12; ++it) {
            const float4 r = row[it];
            s0 += r.x; s1 += r.y; s2 += r.z; s3 += r.w;
        }
        sPr[tid] = (s0+s1) + (s2+s3);
    }
    __syncthreads();   // B2
    if (tid < NV)
        sTot[tid] = (sPr[4*tid] + sPr[4*tid+1]) + (sPr[4*tid+2] + sPr[4*tid+3]);
    __syncthreads();   // B3

    if (COMPUTE_O) {
        // msum_i = 149*A_i + (Csum_b - C_i) + (P[i+150]-P[i]-E149) + Gsum.WmG
        if (tid < 32) {
            const int k = tid;
            float ms = 149.f*a.Abuf[nodeI*32 + k]
                     + a.Csum[b*32 + k] - a.Cin[nodeI*32 + k]
                     + a.P[(i+NN)*32 + k] - a.P[i*32 + k]
                     - a.wm[(2*HD + (NN-1))*32 + k];
#pragma unroll
            for (int t = 0; t < 9; ++t)
                ms = fmaf(sTot[t], a.wm[(2*HD + NE + t)*32 + k], ms);
            sMs[k] = ms;
        }
        if (tid == 64) {   // q/x epilogue (reads sTot only) in parallel
            const float inv = 1.0f / (float)(NN - 1);
            const float ux0 = ((float)NN * xi.x + sTot[9])  * inv;
            const float ux1 = ((float)NN * xi.y + sTot[10]) * inv;
            const float ux2 = ((float)NN * xi.z + sTot[11]) * inv;
            Quat s = {sTot[12], sTot[13], sTot[14], sTot[15]};
            const float nrm = sqrtf(s.w*s.w + s.x*s.x + s.y*s.y + s.z*s.z);
            const float invn = 1.0f / fmaxf(nrm, 1e-12f);
            Quat u = {s.w*invn, s.x*invn, s.y*invn, s.z*invn};
            Quat uq = qmul(qmul(qi, u), qconj(qi));
            a.qout[nodeI*4+0] = uq.w; a.qout[nodeI*4+1] = uq.x;
            a.qout[nodeI*4+2] = uq.y; a.qout[nodeI*4+3] = uq.z;
            a.xout[nodeI*3+0] = ux0;  a.xout[nodeI*3+1] = ux1;
            a.xout[nodeI*3+2] = ux2;
        }
        __syncthreads();   // B4
        if (tid < 64) {
            float acc0 = a.bf[tid], acc1 = 0.f;
#pragma unroll 8
            for (int d2 = 0; d2 < HD; d2 += 2) {
                acc0 = fmaf(sHi[d2],   a.wf[d2*64 + tid],     acc0);
                acc1 = fmaf(sHi[d2+1], a.wf[(d2+1)*64 + tid], acc1);
            }
#pragma unroll 8
            for (int k = 0; k < 32; k += 2) {
                acc0 = fmaf(sMs[k],   a.wf[(HD+k)*64 + tid],   acc0);
                acc1 = fmaf(sMs[k+1], a.wf[(HD+k+1)*64 + tid], acc1);
            }
            sO[tid] = acc0 + acc1;
        }
        __syncthreads();   // B5
        // ---- tail: next layer node work ----
        if (tid < 64) {
            const float hn = fmaxf(sO[tid], 0.f);   // relu
            sHi[tid] = hn;
            if (TAIL_FULL) a.hout[nodeI*64 + tid] = hn;
        }
        __syncthreads();   // B6
        if (tid < 64) {
            const int k   = tid & 31;
            const int off = (tid >= 32) ? 64 : 0;
            float acc = (tid < 32) ? a.bmN[k] : 0.f;
#pragma unroll
            for (int d2 = 0; d2 < 64; ++d2)
                acc = fmaf(sHi[d2], a.wmN[(off+d2)*32 + k], acc);
            if (tid < 32) {
                sA2[k] = acc;
                if (TAIL_FULL) a.Aout[nodeI*32 + k] = acc;
            } else {
                sC2[k] = acc;
                if (TAIL_FULL) {
                    a.Cout[nodeI*32 + k] = acc;
                    atomicAdd(&a.CsumN[b*32 + k], acc);
                }
            }
        }
        __syncthreads();   // B7
        if (tid < 12) {
            const int half = (tid >= 6) ? 1 : 0;
            const int d2 = tid - half*6;
            const float* src = half ? sC2 : sA2;
            float acc = half ? 0.f : a.bqN[d2];
#pragma unroll
            for (int k = 0; k < 32; ++k) acc = fmaf(src[k], a.wqN[k*6 + d2], acc);
            (half ? a.Cdout : a.Adout)[nodeI*8 + d2] = acc;
        }
    } else {
        if (tid == 0) {
            const float inv = 1.0f / (float)(NN - 1);
            const float ux0 = ((float)NN * xi.x + sTot[0]) * inv;
            const float ux1 = ((float)NN * xi.y + sTot[1]) * inv;
            const float ux2 = ((float)NN * xi.z + sTot[2]) * inv;
            Quat s = {sTot[3], sTot[4], sTot[5], sTot[6]};
            const float nrm = sqrtf(s.w*s.w + s.x*s.x + s.y*s.y + s.z*s.z);
            const float invn = 1.0f / fmaxf(nrm, 1e-12f);
            Quat u = {s.w*invn, s.x*invn, s.y*invn, s.z*invn};
            Quat uq = qmul(qmul(qi, u), qconj(qi));
            if (WRITE_OUT) {
                float* op = a.dout + nodeI*7;
                op[0] = uq.w; op[1] = uq.x; op[2] = uq.y; op[3] = uq.z;
                op[4] = ux0;  op[5] = ux1;  op[6] = ux2;
            } else {
                a.qout[nodeI*4+0] = uq.w; a.qout[nodeI*4+1] = uq.x;
                a.qout[nodeI*4+2] = uq.y; a.qout[nodeI*4+3] = uq.z;
                a.xout[nodeI*3+0] = ux0;  a.xout[nodeI*3+1] = ux1;
                a.xout[nodeI*3+2] = ux2;
            }
        }
    }
}

// ---------------------------------------------------------------------------

extern "C" void kernel_launch(void* const* d_in, const int* in_sizes, int n_in,
                              void* d_out, int out_size, void* d_ws, size_t ws_size,
                              hipStream_t stream) {
    const float* quats = (const float*)d_in[0];
    const float* trans = (const float*)d_in[1];
    const float* wm[4] = {(const float*)d_in[5],  (const float*)d_in[11],
                          (const float*)d_in[17], (const float*)d_in[23]};
    const float* bm[4] = {(const float*)d_in[6],  (const float*)d_in[12],
                          (const float*)d_in[18], (const float*)d_in[24]};
    const float* wf[4] = {(const float*)d_in[7],  (const float*)d_in[13],
                          (const float*)d_in[19], (const float*)d_in[25]};
    const float* bf[4] = {(const float*)d_in[8],  (const float*)d_in[14],
                          (const float*)d_in[20], (const float*)d_in[26]};
    const float* wq[4] = {(const float*)d_in[9],  (const float*)d_in[15],
                          (const float*)d_in[21], (const float*)d_in[27]};
    const float* bq[4] = {(const float*)d_in[10], (const float*)d_in[16],
                          (const float*)d_in[22], (const float*)d_in[28]};

    float* ws = (float*)d_ws;
    float* h   = ws;               // 1200*64
    float* A   = h   + NNODE*64;   // 1200*32
    float* CA  = A   + NNODE*32;   // 1200*32
    float* CB  = CA  + NNODE*32;   // 1200*32
    float* Ad  = CB  + NNODE*32;   // 1200*8
    float* CdA = Ad  + NNODE*8;    // 1200*8
    float* CdB = CdA + NNODE*8;    // 1200*8
    float* qA  = CdB + NNODE*8;    // 1200*4
    float* xA  = qA  + NNODE*4;    // 1200*3
    float* qB  = xA  + NNODE*3;    // 1200*4
    float* xB  = qB  + NNODE*4;    // 1200*3
    float* Pp  = xB  + NNODE*3;    // 4*300*32
    float* Edp = Pp  + 4*9600;     // 4*300*8
    float* Gqp = Edp + 4*2400;     // 4*64
    float* Cs  = Gqp + 256;        // 4*256

    // ---- D1 ----
    InitArgs ia;
    ia.quats = quats; ia.trans = trans;
    ia.feats = (const float*)d_in[2];
    ia.tptr  = (const int*)d_in[4];
    for (int l = 0; l < 4; ++l) { ia.wm[l] = wm[l]; ia.wq[l] = wq[l]; }
    ia.bm1 = bm[0]; ia.bq1 = bq[0];
    ia.h = h; ia.A = A; ia.C0 = CA; ia.Ad = Ad; ia.Cd0 = CdA;
    ia.P = Pp; ia.Ed = Edp; ia.Gq = Gqp; ia.Csum = Cs;
    init_kernel<<<dim3(259), dim3(256), 0, stream>>>(ia);

    PairArgs p;
    p.dout = (float*)d_out;

    // ---- P1: layer 1 ----
    p.qcur = quats; p.xcur = trans;
    p.hbuf = h; p.Abuf = A; p.Cin = CA; p.Adin = Ad; p.Cdin = CdA;
    p.Ed = Edp + 0*2400; p.Gq = Gqp + 0*64; p.P = Pp + 0*9600; p.Csum = Cs + 0*256;
    p.wm = wm[0]; p.wf = wf[0]; p.bf = bf[0];
    p.wmN = wm[1]; p.bmN = bm[1]; p.wqN = wq[1]; p.bqN = bq[1];
    p.hout = h; p.Aout = A; p.Adout = Ad; p.Cout = CB; p.Cdout = CdB;
    p.CsumN = Cs + 1*256;
    p.qout = qA; p.xout = xA;
    pair_kernel<30, true, false, true><<<dim3(NNODE), dim3(192), 0, stream>>>(p);

    // ---- P2: layer 2 ----
    p.qcur = qA; p.xcur = xA;
    p.Cin = CB; p.Cdin = CdB;
    p.Ed = Edp + 1*2400; p.Gq = Gqp + 1*64; p.P = Pp + 1*9600; p.Csum = Cs + 1*256;
    p.wm = wm[1]; p.wf = wf[1]; p.bf = bf[1];
    p.wmN = wm[2]; p.bmN = bm[2]; p.wqN = wq[2]; p.bqN = bq[2];
    p.Cout = CA; p.Cdout = CdA;
    p.CsumN = Cs + 2*256;
    p.qout = qB; p.xout = xB;
    pair_kernel<64, true, false, true><<<dim3(NNODE), dim3(192), 0, stream>>>(p);

    // ---- P3: layer 3 (light tail: L4 needs only Ad/Cd) ----
    p.qcur = qB; p.xcur = xB;
    p.Cin = CA; p.Cdin = CdA;
    p.Ed = Edp + 2*2400; p.Gq = Gqp + 2*64; p.P = Pp + 2*9600; p.Csum = Cs + 2*256;
    p.wm = wm[2]; p.wf = wf[2]; p.bf = bf[2];
    p.wmN = wm[3]; p.bmN = bm[3]; p.wqN = wq[3]; p.bqN = bq[3];
    p.Cout = CB; p.Cdout = CdB;
    p.CsumN = Cs + 3*256;
    p.qout = qA; p.xout = xA;
    pair_kernel<64, true, false, false><<<dim3(NNODE), dim3(192), 0, stream>>>(p);

    // ---- P4: layer 4 -> d_out ----
    p.qcur = qA; p.xcur = xA;
    p.Cin = CB; p.Cdin = CdB; p.Adin = Ad;
    p.Ed = Edp + 3*2400; p.Gq = Gqp + 3*64; p.P = Pp + 3*9600; p.Csum = Cs + 3*256;
    p.wm = wm[3]; p.wf = wf[3]; p.bf = bf[3];
    p.wmN = wm[3]; p.bmN = bm[3]; p.wqN = wq[3]; p.bqN = bq[3];  // unused
    p.qout = nullptr; p.xout = nullptr;
    pair_kernel<64, false, true, false><<<dim3(NNODE), dim3(192), 0, stream>>>(p);
}